// Round 9
// baseline (209.272 us; speedup 1.0000x reference)
//
#include <hip/hip_runtime.h>

#define NHID   512
#define NCLS   250
#define CHUNK  200
#define NTOK   2048
#define NOUT   450
#define NBLK   1000            // 250 classes x 4 panel-groups
#define NTHR   256             // 4 waves; 4 blocks/CU -> ~16 waves/CU
#define MAXTOK 64

typedef __attribute__((ext_vector_type(8))) short bf16x8;
typedef __attribute__((ext_vector_type(4))) float f32x4;

#define MFMA(a, b, c) __builtin_amdgcn_mfma_f32_16x16x32_bf16((a), (b), (c), 0, 0, 0)

__device__ __forceinline__ unsigned hpack(unsigned a, unsigned b) {
    return __builtin_amdgcn_perm(a, b, 0x07060302u);
}

// fp32x8 -> hi/lo split bf16x8 (truncate hi; lo = truncate(exact residual))
__device__ __forceinline__ void cvt8(f32x4 va, f32x4 vb, bf16x8& h, bf16x8& l) {
    unsigned u0 = __float_as_uint(va[0]), u1 = __float_as_uint(va[1]);
    unsigned u2 = __float_as_uint(va[2]), u3 = __float_as_uint(va[3]);
    unsigned u4 = __float_as_uint(vb[0]), u5 = __float_as_uint(vb[1]);
    unsigned u6 = __float_as_uint(vb[2]), u7 = __float_as_uint(vb[3]);
    union { unsigned w[4]; bf16x8 v; } H, L;
    H.w[0] = hpack(u1, u0); H.w[1] = hpack(u3, u2);
    H.w[2] = hpack(u5, u4); H.w[3] = hpack(u7, u6);
    float r0 = va[0] - __uint_as_float(u0 & 0xffff0000u);
    float r1 = va[1] - __uint_as_float(u1 & 0xffff0000u);
    float r2 = va[2] - __uint_as_float(u2 & 0xffff0000u);
    float r3 = va[3] - __uint_as_float(u3 & 0xffff0000u);
    float r4 = vb[0] - __uint_as_float(u4 & 0xffff0000u);
    float r5 = vb[1] - __uint_as_float(u5 & 0xffff0000u);
    float r6 = vb[2] - __uint_as_float(u6 & 0xffff0000u);
    float r7 = vb[3] - __uint_as_float(u7 & 0xffff0000u);
    L.w[0] = hpack(__float_as_uint(r1), __float_as_uint(r0));
    L.w[1] = hpack(__float_as_uint(r3), __float_as_uint(r2));
    L.w[2] = hpack(__float_as_uint(r5), __float_as_uint(r4));
    L.w[3] = hpack(__float_as_uint(r7), __float_as_uint(r6));
    h = H.v; l = L.v;
}

// ---- rolling asm load queue: 6 pair-slots in NAMED regs (SROA-trivial) ----
#define WAITB(nn) do { asm volatile("s_waitcnt vmcnt(" #nn ")" ::: "memory"); \
                       __builtin_amdgcn_sched_barrier(0); } while (0)
#define ISSP(S, P) \
    asm volatile("global_load_dwordx4 %0, %1, off offset:%c2" \
        : "=v"(Q##S) : "v"(wrow8), "i"((P) * 128)); \
    asm volatile("global_load_dwordx4 %0, %1, off offset:%c2" \
        : "=v"(R##S) : "v"(wrow8), "i"((P) * 128 + 16));
#define KST(S, s) { \
    const char* ab_ = (const char*)Afrag + n * 2048 + (s) * 128; \
    bf16x8 ah_ = *(const bf16x8*)(ab_ + (((q*2    ) ^ (n&7)) << 4)); \
    bf16x8 al_ = *(const bf16x8*)(ab_ + (((q*2 + 1) ^ (n&7)) << 4)); \
    bf16x8 bh_, bl_; cvt8(Q##S, R##S, bh_, bl_); \
    acc = MFMA(ah_, bh_, acc); \
    acc = MFMA(al_, bh_, acc); \
    acc = MFMA(ah_, bl_, acc); }

// one column-group (of 8) of a p_class unit, 2-deep register pipeline
__device__ __forceinline__ void class_unit(int u, int w8, int lane, int n, int q,
                                           const float* __restrict__ x,
                                           const float* __restrict__ Wc,
                                           const float* __restrict__ bc,
                                           float* __restrict__ out) {
    const int mt = u >> 1, hn = u & 1;
    const int g4 = (w8 >> 2) & 1, kk = w8 & 3;
    const int rC = (hn * 8 + g4 * 4 + kk) * 16 + n;
    const bool rv = rC < NCLS;
    const int  rc = rv ? rC : NCLS - 1;
    const float* ap = x  + (size_t)(mt * 16 + n) * NHID + q * 8;
    const float* bp = Wc + (size_t)rc * NHID + q * 8;
    const float bias = bc[rc];
    f32x4 acc = {0.f, 0.f, 0.f, 0.f};
    f32x4 qa[2][2], qb[2][2];
    #pragma unroll
    for (int j = 0; j < 2; ++j) {
        qa[j][0] = *(const f32x4*)(ap + j * 32);
        qa[j][1] = *(const f32x4*)(ap + j * 32 + 4);
        qb[j][0] = *(const f32x4*)(bp + j * 32);
        qb[j][1] = *(const f32x4*)(bp + j * 32 + 4);
    }
    #pragma unroll 2
    for (int s = 0; s < 16; ++s) {
        const int b = s & 1;
        bf16x8 ah, al, bh, bl;
        cvt8(qa[b][0], qa[b][1], ah, al);
        cvt8(qb[b][0], qb[b][1], bh, bl);
        acc = MFMA(ah, bh, acc);
        acc = MFMA(al, bh, acc);
        acc = MFMA(ah, bl, acc);
        if (s + 2 < 16) {
            qa[b][0] = *(const f32x4*)(ap + (s + 2) * 32);
            qa[b][1] = *(const f32x4*)(ap + (s + 2) * 32 + 4);
            qb[b][0] = *(const f32x4*)(bp + (s + 2) * 32);
            qb[b][1] = *(const f32x4*)(bp + (s + 2) * 32 + 4);
        }
    }
    if (rv) {
        #pragma unroll
        for (int i = 0; i < 4; ++i)
            out[(size_t)(mt * 16 + q * 4 + i) * NOUT + rc] = acc[i] + bias;
    }
}

__global__ __launch_bounds__(NTHR, 4)
void cbd_fused(const float* __restrict__ x,  const float* __restrict__ Wc,
               const float* __restrict__ bc, const float* __restrict__ Ww,
               const float* __restrict__ bw, const int* __restrict__ cls_idx,
               float* __restrict__ out)
{
    __shared__ short Afrag[16384];   // 16 tok x 16 ks x 4 q x (ah|al), 32 KB
    __shared__ int   toktmp[MAXTOK];

    const int tid  = threadIdx.x;
    const int wid  = tid >> 6;        // 0..3
    const int lane = tid & 63;
    const int n    = lane & 15;
    const int q    = lane >> 4;
    const int c    = blockIdx.x >> 2; // class
    const int g    = blockIdx.x & 3;  // panel-group: 0..2 -> 4 panels; 3 -> panel 12

    // ---- per-wave redundant token scan (identical values per wave) ----
    int myvals[32];
    #pragma unroll
    for (int it = 0; it < 8; ++it) {
        int4 v = *(const int4*)&cls_idx[it * 256 + lane * 4];
        myvals[it*4+0] = v.x; myvals[it*4+1] = v.y;
        myvals[it*4+2] = v.z; myvals[it*4+3] = v.w;
    }
    int cnt = 0;
    #pragma unroll
    for (int j = 0; j < 32; ++j) {
        int idx  = (j >> 2) * 256 + lane * 4 + (j & 3);
        bool hit = (myvals[j] == c);
        unsigned long long m = __ballot(hit);
        if (hit) {
            int pos = cnt + (int)__popcll(m & ((1ull << lane) - 1ull));
            if (pos < MAXTOK) toktmp[pos] = idx;
        }
        cnt += (int)__popcll(m);
    }
    const int cnt1 = cnt < 16 ? cnt : 16;

    int tkS[4]; bool msk[4];
    if (cnt) {
        int mytokA = toktmp[n < cnt1 ? n : cnt1 - 1];
        #pragma unroll
        for (int i = 0; i < 4; ++i) {
            tkS[i] = __shfl(mytokA, q * 4 + i);
            msk[i] = (q * 4 + i) < cnt1;
        }
        // ---- stage A once: split-bf16 fragments, XOR-swizzled slots ----
        #pragma unroll
        for (int rep = 0; rep < 4; ++rep) {
            int job = rep * 256 + tid;
            int tok = job >> 6, s = (job >> 2) & 15, qq = job & 3;
            int ti  = toktmp[tok < cnt1 ? tok : cnt1 - 1];
            const float* xp = x + (size_t)ti * NHID + s * 32 + qq * 8;
            f32x4 a0 = *(const f32x4*)xp, a1 = *(const f32x4*)(xp + 4);
            bf16x8 hh, ll; cvt8(a0, a1, hh, ll);
            char* ab = (char*)Afrag + tok * 2048 + s * 128;
            *(bf16x8*)(ab + (((qq * 2    ) ^ (tok & 7)) << 4)) = hh;
            *(bf16x8*)(ab + (((qq * 2 + 1) ^ (tok & 7)) << 4)) = ll;
        }
    }
    __syncthreads();

    // ================= p_words: rolling asm-queue pipeline ==================
    const int P = (g < 3) ? (g * 4 + wid) : 12;   // panel this wave owns
    if (cnt && (g < 3 || wid == 0)) {
        const int r  = P * 16 + n;
        const int rr = r < CHUNK ? r : CHUNK - 1;
        const char* wrow8 =
            (const char*)(Ww + ((size_t)c * CHUNK + rr) * NHID + q * 8);
        float bias = bw[c * CHUNK + rr];

        f32x4 Q0, Q1, Q2, Q3, Q4, Q5, R0, R1, R2, R3, R4, R5;
        f32x4 acc = {0.f, 0.f, 0.f, 0.f};

        WAITB(0);                       // clean vmcnt base (bias, prior stores)
        ISSP(0, 0)  ISSP(1, 1)  ISSP(2, 2)  ISSP(3, 3)  ISSP(4, 4)  ISSP(5, 5)

        WAITB(10); KST(0, 0)  ISSP(0, 6)
        WAITB(10); KST(1, 1)  ISSP(1, 7)
        WAITB(10); KST(2, 2)  ISSP(2, 8)
        WAITB(10); KST(3, 3)  ISSP(3, 9)
        WAITB(10); KST(4, 4)  ISSP(4, 10)
        WAITB(10); KST(5, 5)  ISSP(5, 11)
        WAITB(10); KST(0, 6)  ISSP(0, 12)
        WAITB(10); KST(1, 7)  ISSP(1, 13)
        WAITB(10); KST(2, 8)  ISSP(2, 14)
        WAITB(10); KST(3, 9)  ISSP(3, 15)
        WAITB(10); KST(4, 10)
        WAITB(8);  KST(5, 11)
        WAITB(6);  KST(0, 12)
        WAITB(4);  KST(1, 13)
        WAITB(2);  KST(2, 14)
        WAITB(0);  KST(3, 15)

        if (r < CHUNK) {
            #pragma unroll
            for (int i = 0; i < 4; ++i)
                if (msk[i])
                    out[(size_t)tkS[i] * NOUT + NCLS + r] = acc[i] + bias;
        }
    }

    // ====== p_class: group-3 spare waves, 3 column-group calls each =========
    if (g == 3 && wid >= 1) {
        const int base = (c * 3 + (wid - 1)) * 3;
        #pragma unroll
        for (int k = 0; k < 3; ++k) {
            int t = base + k;
            if (t < 2048)
                class_unit(t >> 3, t & 7, lane, n, q, x, Wc, bc, out);
        }
    }

    // ============ rare overflow (cnt>16): scalar-FMA residual tail ==========
    if (g == 3 && cnt > 16) {
        const int cw = cnt < MAXTOK ? cnt : MAXTOK;
        const int ov = cw - 16;
        for (int j = tid; j < ov * CHUNK; j += NTHR) {
            const int gg = j / CHUNK;
            const int rr = j - gg * CHUNK;
            const int ti = toktmp[16 + gg];
            const float4* wr = (const float4*)(Ww + ((size_t)c * CHUNK + rr) * NHID);
            const float4* xr = (const float4*)(x + (size_t)ti * NHID);
            float s0 = 0.f, s1 = 0.f, s2 = 0.f, s3 = 0.f;
            #pragma unroll 4
            for (int k = 0; k < 128; ++k) {
                float4 a = wr[k], b = xr[k];
                s0 += a.x * b.x; s1 += a.y * b.y;
                s2 += a.z * b.z; s3 += a.w * b.w;
            }
            out[(size_t)ti * NOUT + NCLS + rr] =
                (s0 + s1) + (s2 + s3) + bw[c * CHUNK + rr];
        }
    }
}

extern "C" void kernel_launch(void* const* d_in, const int* in_sizes, int n_in,
                              void* d_out, int out_size, void* d_ws, size_t ws_size,
                              hipStream_t stream) {
    const float* x   = (const float*)d_in[0];
    const float* Wc  = (const float*)d_in[1];
    const float* bc  = (const float*)d_in[2];
    const float* Ww  = (const float*)d_in[3];
    const float* bw  = (const float*)d_in[4];
    const int*   cls = (const int*)d_in[5];
    float* out = (float*)d_out;
    hipLaunchKernelGGL(cbd_fused, dim3(NBLK), dim3(NTHR), 0, stream,
                       x, Wc, bc, Ww, bw, cls, out);
}

// Round 10
// 174.690 us; speedup vs baseline: 1.1980x; 1.1980x over previous
//
#include <hip/hip_runtime.h>

#define NHID   512
#define NCLS   250
#define CHUNK  200
#define NTOK   2048
#define NOUT   450
#define NPAN   13              // ceil(CHUNK/16) 16-row word panels per class
#define NWB    (NCLS * NPAN)   // 3250 p_words blocks
#define NCB    256             // p_class blocks (dispatched first)
#define NBLK   (NWB + NCB)     // 3506
#define NTHR   64              // 1 wave per block
#define MAXTOK 64

typedef __attribute__((ext_vector_type(8))) short bf16x8;
typedef __attribute__((ext_vector_type(4))) float f32x4;

#define MFMA(a, b, c) __builtin_amdgcn_mfma_f32_16x16x32_bf16((a), (b), (c), 0, 0, 0)

// float offset of k-step s within a swizzled LDS row (halves of 256 floats)
#define BOFF(s) ((((s) >> 3) * 256) + (((s) & 7) * 32))

__device__ __forceinline__ unsigned hpack(unsigned a, unsigned b) {
    return __builtin_amdgcn_perm(a, b, 0x07060302u);
}

// fp32x8 -> hi/lo split bf16x8 (truncate hi; lo = truncate(exact residual))
__device__ __forceinline__ void cvt8(float4 va, float4 vb, bf16x8& h, bf16x8& l) {
    unsigned u0 = __float_as_uint(va.x), u1 = __float_as_uint(va.y);
    unsigned u2 = __float_as_uint(va.z), u3 = __float_as_uint(va.w);
    unsigned u4 = __float_as_uint(vb.x), u5 = __float_as_uint(vb.y);
    unsigned u6 = __float_as_uint(vb.z), u7 = __float_as_uint(vb.w);
    union { unsigned w[4]; bf16x8 v; } H, L;
    H.w[0] = hpack(u1, u0); H.w[1] = hpack(u3, u2);
    H.w[2] = hpack(u5, u4); H.w[3] = hpack(u7, u6);
    float r0 = va.x - __uint_as_float(u0 & 0xffff0000u);
    float r1 = va.y - __uint_as_float(u1 & 0xffff0000u);
    float r2 = va.z - __uint_as_float(u2 & 0xffff0000u);
    float r3 = va.w - __uint_as_float(u3 & 0xffff0000u);
    float r4 = vb.x - __uint_as_float(u4 & 0xffff0000u);
    float r5 = vb.y - __uint_as_float(u5 & 0xffff0000u);
    float r6 = vb.z - __uint_as_float(u6 & 0xffff0000u);
    float r7 = vb.w - __uint_as_float(u7 & 0xffff0000u);
    L.w[0] = hpack(__float_as_uint(r1), __float_as_uint(r0));
    L.w[1] = hpack(__float_as_uint(r3), __float_as_uint(r2));
    L.w[2] = hpack(__float_as_uint(r5), __float_as_uint(r4));
    L.w[3] = hpack(__float_as_uint(r7), __float_as_uint(r6));
    h = H.v; l = L.v;
}

// async 16B/lane global->LDS (wave-uniform LDS base; HW adds lane*16;
// GLOBAL source address is per-lane -> source-side swizzle is legal)
__device__ __forceinline__ void async16(const float* g, float* lds_base) {
    __builtin_amdgcn_global_load_lds(
        (const __attribute__((address_space(1))) unsigned*)g,
        (__attribute__((address_space(3))) unsigned*)lds_base, 16, 0, 0);
}

__device__ __forceinline__ void lds_fence_wave() {
    __builtin_amdgcn_wave_barrier();
    asm volatile("s_waitcnt lgkmcnt(0)" ::: "memory");
    __builtin_amdgcn_wave_barrier();
}

__global__ __launch_bounds__(NTHR)
void cbd_fused(const float* __restrict__ x,  const float* __restrict__ Wc,
               const float* __restrict__ bc, const float* __restrict__ Ww,
               const float* __restrict__ bw, const int* __restrict__ cls_idx,
               float* __restrict__ out)
{
    __shared__ float Bbuf[16 * 512];   // 32 KB swizzled B panel (whole block tile)
    __shared__ int   toktmp[MAXTOK];

    const int bid  = blockIdx.x;
    const int lane = threadIdx.x;     // 64-thread block = one wave
    const int n    = lane & 15;       // fragment row slot
    const int q    = lane >> 4;      // k-quad

    if (bid < NCB) {
        // ======== p_class tiles (L2-hot Wc), 2-deep register pipeline ========
        const int mt = bid >> 1, hn = bid & 1;
        const float* ap = x + (size_t)(mt * 16 + n) * NHID + q * 8;
        #pragma unroll
        for (int g4 = 0; g4 < 2; ++g4) {
            const float* bp[4]; float bias[4]; int col[4]; bool rv[4];
            #pragma unroll
            for (int k = 0; k < 4; ++k) {
                int r = (hn * 8 + g4 * 4 + k) * 16 + n;
                rv[k] = r < NCLS;
                int rc = rv[k] ? r : NCLS - 1;
                bp[k]   = Wc + (size_t)rc * NHID + q * 8;
                bias[k] = bc[rc];
                col[k]  = rc;
            }
            f32x4 acc[4] = {{0,0,0,0},{0,0,0,0},{0,0,0,0},{0,0,0,0}};
            float4 qa[2][2], qb[2][8];
            #pragma unroll
            for (int j = 0; j < 2; ++j) {
                qa[j][0] = *(const float4*)(ap + j * 32);
                qa[j][1] = *(const float4*)(ap + j * 32 + 4);
                #pragma unroll
                for (int k = 0; k < 4; ++k) {
                    qb[j][2*k]   = *(const float4*)(bp[k] + j * 32);
                    qb[j][2*k+1] = *(const float4*)(bp[k] + j * 32 + 4);
                }
            }
            #pragma unroll 2
            for (int s = 0; s < 16; ++s) {
                const int b = s & 1;
                bf16x8 ah, al; cvt8(qa[b][0], qa[b][1], ah, al);
                #pragma unroll
                for (int k = 0; k < 4; ++k) {
                    bf16x8 bh, bl; cvt8(qb[b][2*k], qb[b][2*k+1], bh, bl);
                    acc[k] = MFMA(ah, bh, acc[k]);
                    acc[k] = MFMA(al, bh, acc[k]);
                    acc[k] = MFMA(ah, bl, acc[k]);
                }
                if (s + 2 < 16) {
                    qa[b][0] = *(const float4*)(ap + (s+2) * 32);
                    qa[b][1] = *(const float4*)(ap + (s+2) * 32 + 4);
                    #pragma unroll
                    for (int k = 0; k < 4; ++k) {
                        qb[b][2*k]   = *(const float4*)(bp[k] + (s+2) * 32);
                        qb[b][2*k+1] = *(const float4*)(bp[k] + (s+2) * 32 + 4);
                    }
                }
            }
            #pragma unroll
            for (int k = 0; k < 4; ++k)
                if (rv[k]) {
                    #pragma unroll
                    for (int i = 0; i < 4; ++i)
                        out[(size_t)(mt * 16 + q * 4 + i) * NOUT + col[k]]
                            = acc[k][i] + bias[k];
                }
        }
        return;
    }

    // ================= p_words: one (class, 16-row panel) per wave ===========
    const int wb0 = bid - NCB;
    // XCD-contiguous bijective remap (m204): the dispatcher assigns consecutive
    // blockIdx round-robin to the 8 XCDs. Give XCD k a CONTIGUOUS wbid range so
    // each XCD's 32 CUs sweep ONE contiguous ~12.8 MB Ww region in temporal
    // order: DRAM pages stay open, per-XCD L2 sees a sequential miss stream.
    // NWB=3250: q=406, r=2 -> XCDs 0,1 own 407 slots; XCDs 2..7 own 406.
    const int xcd  = wb0 & 7;
    const int slot = wb0 >> 3;
    const int base = (xcd < 2) ? xcd * 407 : 2 * 407 + (xcd - 2) * 406;
    const int wb   = base + slot;

    const int c = wb / NPAN;
    const int p = wb - c * NPAN;

    const int r  = p * 16 + n;
    const int rr = r < CHUNK ? r : CHUNK - 1;   // clamp pad rows (store-masked)

    // ---- load cls_idx + bias FIRST and pin them, so NO compiler waitcnt
    //      after this point can force a drain of the DMA queue ----
    int myvals[32];
    #pragma unroll
    for (int it = 0; it < 8; ++it) {
        int4 v = *(const int4*)&cls_idx[it * 256 + lane * 4];
        myvals[it*4+0] = v.x; myvals[it*4+1] = v.y;
        myvals[it*4+2] = v.z; myvals[it*4+3] = v.w;
    }
    float bias = bw[c * CHUNK + rr];
    #pragma unroll
    for (int it = 0; it < 8; ++it)
        asm volatile("" :: "v"(myvals[it*4]), "v"(myvals[it*4+1]),
                           "v"(myvals[it*4+2]), "v"(myvals[it*4+3]));
    asm volatile("" :: "v"(bias));

    // ---- DMA the whole 32 KB B panel, source-side XOR swizzle:
    //      LDS[j][h*256 + 4*l + e] = W[rr_j][h*256 + 4*(l^(j&7)) + e]
    //      => reader applies the same XOR on its 16B-slot index ----
    #pragma unroll
    for (int j = 0; j < 16; ++j) {
        int rj = p * 16 + j; if (rj > CHUNK - 1) rj = CHUNK - 1;
        const float* srow = Ww + ((size_t)c * CHUNK + rj) * NHID;
        const int lsw = (lane ^ (j & 7)) << 2;
        async16(srow + lsw,       &Bbuf[j * 512]);
        async16(srow + 256 + lsw, &Bbuf[j * 512 + 256]);
    }

    // ---- token membership scan (pure VALU now; overlaps DMA flight) ----
    int cnt = 0;
    #pragma unroll
    for (int j = 0; j < 32; ++j) {
        int idx  = (j >> 2) * 256 + lane * 4 + (j & 3);
        bool hit = (myvals[j] == c);
        unsigned long long m = __ballot(hit);
        if (hit) {
            int pos = cnt + (int)__popcll(m & ((1ull << lane) - 1ull));
            if (pos < MAXTOK) toktmp[pos] = idx;
        }
        cnt += (int)__popcll(m);
    }
    if (cnt == 0) {   // empty class: must drain DMA before LDS is reassigned
        asm volatile("s_waitcnt vmcnt(0)" ::: "memory");
        return;
    }
    const int cntc = cnt < MAXTOK ? cnt : MAXTOK;
    lds_fence_wave();

    // swizzled per-lane read bases: two 16B slots per k-step
    const float* Bb0 = Bbuf + n * 512 + (((q * 8))     ^ ((n & 7) << 2));
    const float* Bb1 = Bbuf + n * 512 + (((q * 8) + 4) ^ ((n & 7) << 2));

    // ---- token-slot groups (almost always exactly one: mean cnt = 8.2) ----
    for (int sb = 0; sb < cntc; sb += 16) {
        int slotn = sb + n;
        int mytok = toktmp[slotn < cntc ? slotn : 0];
        int tkS[4]; bool msk[4];
        #pragma unroll
        for (int i = 0; i < 4; ++i) {
            int m = q * 4 + i;
            tkS[i] = __shfl(mytok, m);
            msk[i] = (sb + m) < cntc;
        }
        const float* apx = x + (size_t)mytok * NHID + q * 8;

        // A chunks 0,1 direct-to-register (8 loads, newer than the 32 DMA)
        float4 pa[2][4];
        #pragma unroll
        for (int j = 0; j < 2; ++j)
            #pragma unroll
            for (int t = 0; t < 2; ++t) {
                pa[j][2*t]   = *(const float4*)(apx + (2*j + t) * 32);
                pa[j][2*t+1] = *(const float4*)(apx + (2*j + t) * 32 + 4);
            }
        // in-order retirement: <=8 outstanding left => all 32 DMA landed,
        // A chunk loads may still be in flight
        asm volatile("s_waitcnt vmcnt(8)" ::: "memory");

        f32x4 acc = {0.f, 0.f, 0.f, 0.f};
        #pragma unroll
        for (int j = 0; j < 8; ++j) {          // 8 chunks x 2 k-steps, full unroll
            const int b = j & 1;
            #pragma unroll
            for (int t = 0; t < 2; ++t) {
                const int s = 2 * j + t;
                bf16x8 ah, al, bh, bl;
                cvt8(pa[b][2*t], pa[b][2*t+1], ah, al);
                float4 b0 = *(const float4*)(Bb0 + BOFF(s));
                float4 b1 = *(const float4*)(Bb1 + BOFF(s));
                cvt8(b0, b1, bh, bl);
                acc = MFMA(ah, bh, acc);
                acc = MFMA(al, bh, acc);
                acc = MFMA(ah, bl, acc);
            }
            if (j + 2 < 8) {                   // refill buffer b with chunk j+2
                #pragma unroll
                for (int t = 0; t < 2; ++t) {
                    const int s = 2 * (j + 2) + t;
                    pa[b][2*t]   = *(const float4*)(apx + s * 32);
                    pa[b][2*t+1] = *(const float4*)(apx + s * 32 + 4);
                }
            }
        }

        if (r < CHUNK) {
            #pragma unroll
            for (int i = 0; i < 4; ++i)
                if (msk[i])
                    out[(size_t)tkS[i] * NOUT + NCLS + r] = acc[i] + bias;
        }
    }
}

extern "C" void kernel_launch(void* const* d_in, const int* in_sizes, int n_in,
                              void* d_out, int out_size, void* d_ws, size_t ws_size,
                              hipStream_t stream) {
    const float* x   = (const float*)d_in[0];
    const float* Wc  = (const float*)d_in[1];
    const float* bc  = (const float*)d_in[2];
    const float* Ww  = (const float*)d_in[3];
    const float* bw  = (const float*)d_in[4];
    const int*   cls = (const int*)d_in[5];
    float* out = (float*)d_out;
    hipLaunchKernelGGL(cbd_fused, dim3(NBLK), dim3(NTHR), 0, stream,
                       x, Wc, bc, Ww, bw, cls, out);
}